// Round 19
// baseline (172.761 us; speedup 1.0000x reference)
//
#include <hip/hip_runtime.h>
#include <math.h>

#define NBATCH 4
#define NPTS   8192
#define KNN    8
#define NCH    4096
#define SLICES 16
#define SLEN   512               // candidates per slice-wave
#define NWIN   8                 // windows per slice
#define WLEN   64                // candidates per window
#define CTR_OFF 56
#define PB_OFF  256                                  // f32 pair buffer, 32B/pair
#define SCAN_BLOCKS (NBATCH * (NPTS / 64))           // 512

typedef float v2f __attribute__((ext_vector_type(2)));

__device__ __forceinline__ unsigned umin32(unsigned a, unsigned b) { return a < b ? a : b; }

// single-block insert: 8 instrs, bd pinned via tied "+v", in-place descending
// order reads only pre-block values => depth-1 sorted insert (ascending top-8).
// Used ONLY in the merge phases (not the hot scan loop).
#define INSERT8(bd, key)                                          \
    asm("v_med3_u32 %7, %8, %6, %7\n\t"                           \
        "v_med3_u32 %6, %8, %5, %6\n\t"                           \
        "v_med3_u32 %5, %8, %4, %5\n\t"                           \
        "v_med3_u32 %4, %8, %3, %4\n\t"                           \
        "v_med3_u32 %3, %8, %2, %3\n\t"                           \
        "v_med3_u32 %2, %8, %1, %2\n\t"                           \
        "v_med3_u32 %1, %8, %0, %1\n\t"                           \
        "v_min_u32  %0, %0, %8"                                   \
        : "+v"(bd[0]), "+v"(bd[1]), "+v"(bd[2]), "+v"(bd[3]),     \
          "+v"(bd[4]), "+v"(bd[5]), "+v"(bd[6]), "+v"(bd[7])      \
        : "v"(key))

// prep (512 thr x 32 blocks): pred -> f32 pair buffer {x0,x1,y0,y1,z0,z1,w0,w1}
__global__ __launch_bounds__(512) void prep_kernel(const float* __restrict__ pts,
                                                   float* __restrict__ pb) {
    const int pi = blockIdx.x * 512 + threadIdx.x;
    const float* s = pts + (size_t)pi * 6;
    const float x0 = s[0], y0 = s[1], z0 = s[2];
    const float x1 = s[3], y1 = s[4], z1 = s[5];
    float4* o = reinterpret_cast<float4*>(pb + (size_t)pi * 8);
    o[0] = make_float4(x0, x1, y0, y1);
    o[1] = make_float4(z0, z1, x0 * x0 + y0 * y0 + z0 * z0,
                               x1 * x1 + y1 * y1 + z1 * z1);
}

// Mega kernel: 512 blocks x 1024 thr (perfect 2 blocks/CU, no tail).
// Phase A (prologue, ~2µs, embedded in every block -> zero extra blocks):
//   - recon MSE: 48 float4/block (wave w, lanes 0-2), percep: 2 float4 (wave 0)
//   - boundary: 8 queries/block (SGPR-held) vs ALL 4096 c2 pts; wave w takes
//     256 pts, 4/lane via coalesced float4 loads; per-query shfl-min reduce.
// Phase B: EXACT round-11 continuity scan: 16 slice-waves x 64 shared queries,
//   wave-uniform scalar s_load_dwordx4 stream, window-min keys (26-bit d2 |
//   6-bit idx), exact med3 top-8 merge (self filtered by index), closed-form
//   deviation sum. No finalize here (threadfence-per-block costs ~9µs — r18).
__global__ __launch_bounds__(1024, 8) void mega_kernel(const float* __restrict__ pb,
                                                       const float* __restrict__ a,
                                                       const float* __restrict__ bt,
                                                       const float* __restrict__ a2,
                                                       const float* __restrict__ b2,
                                                       const float* __restrict__ c1,
                                                       const float* __restrict__ c2,
                                                       double* __restrict__ acc) {
    __shared__ unsigned mrg[SLICES][KNN][64];   // 32 KB; phase A aliases corner
    const int t    = threadIdx.x;
    const int lane = t & 63;
    const int w    = __builtin_amdgcn_readfirstlane(t >> 6);   // wave id (SGPR)
    const int blk  = blockIdx.x;

    // ---------------- Phase A: MSE + boundary prologue ----------------
    {
        float* mnb = (float*)mrg;               // [16][8] floats
        // MSE partials (wave-local shfl reduce -> atomicAdd)
        float s0 = 0.f, s1 = 0.f;
        if (lane < 3) {                         // recon: 16 waves x 3 float4
            const int i = blk * 48 + w * 3 + lane;
            const float4 va = reinterpret_cast<const float4*>(a)[i];
            const float4 vb = reinterpret_cast<const float4*>(bt)[i];
            const float dx = va.x - vb.x, dy = va.y - vb.y;
            const float dz = va.z - vb.z, dw = va.w - vb.w;
            s0 = dx * dx + dy * dy + dz * dz + dw * dw;
        }
        if (w == 0 && lane < 2) {               // percep: 2 float4
            const int i = blk * 2 + lane;
            const float4 va = reinterpret_cast<const float4*>(a2)[i];
            const float4 vb = reinterpret_cast<const float4*>(b2)[i];
            const float dx = va.x - vb.x, dy = va.y - vb.y;
            const float dz = va.z - vb.z, dw = va.w - vb.w;
            s1 = dx * dx + dy * dy + dz * dz + dw * dw;
        }
#pragma unroll
        for (int o = 2; o > 0; o >>= 1) { s0 += __shfl_down(s0, o, 64); s1 += __shfl_down(s1, o, 64); }
        if (lane == 0) {
            if (s0 != 0.f) atomicAdd(&acc[0], (double)s0);
            if (w == 0) atomicAdd(&acc[1], (double)s1);
        }

        // boundary: 8 queries (uniform scalar loads) vs this wave's 256 c2 pts
        const float* qb = c1 + (size_t)blk * 24;
        float qx[8], qy[8], qz[8];
#pragma unroll
        for (int q = 0; q < 8; ++q) {
            qx[q] = qb[q * 3 + 0]; qy[q] = qb[q * 3 + 1]; qz[q] = qb[q * 3 + 2];
        }
        float m[8];
#pragma unroll
        for (int q = 0; q < 8; ++q) m[q] = 3.0e38f;
        const float* Sp = c2 + (size_t)(w * 256 + lane * 4) * 3;   // 48B/lane
        const float4 u0 = *reinterpret_cast<const float4*>(Sp + 0);
        const float4 u1 = *reinterpret_cast<const float4*>(Sp + 4);
        const float4 u2 = *reinterpret_cast<const float4*>(Sp + 8);
        const float cxs[4] = {u0.x, u0.w, u1.z, u2.y};
        const float cys[4] = {u0.y, u1.x, u1.w, u2.z};
        const float czs[4] = {u0.z, u1.y, u2.x, u2.w};
#pragma unroll
        for (int p = 0; p < 4; ++p) {
#pragma unroll
            for (int q = 0; q < 8; ++q) {
                const float dx = cxs[p] - qx[q];
                const float dy = cys[p] - qy[q];
                const float dz = czs[p] - qz[q];
                m[q] = fminf(m[q], fmaf(dx, dx, fmaf(dy, dy, dz * dz)));
            }
        }
#pragma unroll
        for (int q = 0; q < 8; ++q) {
#pragma unroll
            for (int o = 32; o > 0; o >>= 1) m[q] = fminf(m[q], __shfl_down(m[q], o, 64));
        }
        if (lane == 0) {
#pragma unroll
            for (int q = 0; q < 8; ++q) mnb[w * 8 + q] = m[q];
        }
        __syncthreads();
        if (w == 0 && lane < 8) {
            float mm = mnb[lane];
#pragma unroll
            for (int s = 1; s < 16; ++s) mm = fminf(mm, mnb[s * 8 + lane]);
            const float d = sqrtf(mm);
            const bool in = d < 0.1f;
            float sc = in ? d : 0.f;
            float sn = in ? 1.f : 0.f;
#pragma unroll
            for (int o = 4; o > 0; o >>= 1) {
                sc += __shfl_down(sc, o, 64);
                sn += __shfl_down(sn, o, 64);
            }
            if (lane == 0) {
                atomicAdd(&acc[3], (double)sc);
                atomicAdd(&acc[4], (double)sn);
            }
        }
        __syncthreads();   // mnb dead; mrg reusable
    }

    // ---------------- Phase B: round-11 continuity scan ----------------
    const int nqw  = NPTS / 64;
    const int b    = blk / nqw;
    const int q0   = (blk % nqw) * 64;
    const float* __restrict__ B = pb + (size_t)b * (NPTS / 2) * 8;

    const int qi = q0 + lane;
    const float* qp = B + (size_t)(qi >> 1) * 8;
    const int e = qi & 1;
    const float qx = qp[0 + e], qy = qp[2 + e], qz = qp[4 + e], qw = qp[6 + e];
    const v2f qnp2 = {qw + 1e-6f, qw + 1e-6f};
    const v2f m2x2 = {-2.f * qx, -2.f * qx};
    const v2f m2y2 = {-2.f * qy, -2.f * qy};
    const v2f m2z2 = {-2.f * qz, -2.f * qz};

    const float* __restrict__ Sp = B + (size_t)w * SLEN * 4;
    const unsigned jb = (unsigned)(w * SLEN);
    unsigned keyout[NWIN];

#pragma unroll
    for (int wi = 0; wi < NWIN; ++wi) {
        const float* __restrict__ Wp = Sp + wi * (WLEN * 4);
        unsigned wmA = 0xFFFFFFFFu, wmB = 0xFFFFFFFFu;
#pragma unroll
        for (int j = 0; j < WLEN / 2; ++j) {
            const float4 ab = *reinterpret_cast<const float4*>(Wp + j * 8);      // x0 x1 y0 y1
            const float4 cd = *reinterpret_cast<const float4*>(Wp + j * 8 + 4);  // z0 z1 w0 w1
            const v2f xp = {ab.x, ab.y}, yp = {ab.z, ab.w};
            const v2f zp = {cd.x, cd.y}, wp = {cd.z, cd.w};
            v2f s2 = wp + qnp2;
            s2 = __builtin_elementwise_fma(zp, m2z2, s2);
            s2 = __builtin_elementwise_fma(yp, m2y2, s2);
            s2 = __builtin_elementwise_fma(xp, m2x2, s2);
            const unsigned k0 = (__float_as_uint(s2.x) & 0xFFFFFFC0u) | (unsigned)(2 * j);
            const unsigned k1 = (__float_as_uint(s2.y) & 0xFFFFFFC0u) | (unsigned)(2 * j + 1);
            wmA = umin32(wmA, k0);
            wmB = umin32(wmB, k1);
        }
        const unsigned wm = umin32(wmA, wmB);
        const unsigned base = jb + (unsigned)(wi * WLEN);   // scalar per window
        keyout[wi] = (wm & 0xFFFFE000u) | base | (wm & 63u);
    }

#pragma unroll
    for (int wi = 0; wi < NWIN; ++wi) mrg[w][wi][lane] = keyout[wi];
    __syncthreads();

    // stage 1: waves 0..3 each merge 4 slices' window minima (self filtered)
    if (w < 4) {
        const unsigned selfidx = (unsigned)qi;
        unsigned best[KNN];
#pragma unroll
        for (int s = 0; s < KNN; ++s) best[s] = 0xFFFFFFFFu;
        for (int sl = 4 * w; sl < 4 * w + 4; ++sl) {
#pragma unroll
            for (int u = 0; u < KNN; ++u) {
                unsigned key = mrg[sl][u][lane];
                key = ((key & 0x1FFFu) == selfidx) ? 0xFFFFFFFFu : key;
                INSERT8(best, key);
            }
        }
#pragma unroll
        for (int s = 0; s < KNN; ++s) mrg[4 * w][s][lane] = best[s];
    }
    __syncthreads();

    // stage 2: wave 0 merges the 4 partials; closed-form deviation sum
    if (w == 0) {
        unsigned best[KNN];
#pragma unroll
        for (int s = 0; s < KNN; ++s) best[s] = 0xFFFFFFFFu;
        for (int g = 0; g < 4; ++g) {
#pragma unroll
            for (int u = 0; u < KNN; ++u) {
                const unsigned key = mrg[4 * g][u][lane];
                INSERT8(best, key);
            }
        }
        float sx = 0.f, sy = 0.f, sz = 0.f, sw = 0.f;
#pragma unroll
        for (int s = 0; s < KNN; ++s) {
            const unsigned n = best[s] & 0x1FFFu;
            const float* np = B + (size_t)(n >> 1) * 8 + (n & 1);
            sx += np[0]; sy += np[2]; sz += np[4]; sw += np[6];
        }
        float ssum = sw - (sx * sx + sy * sy + sz * sz) * (1.f / KNN);
#pragma unroll
        for (int o = 32; o > 0; o >>= 1) ssum += __shfl_down(ssum, o, 64);
        if (lane == 0) atomicAdd(&acc[2], (double)ssum);
    }
}

__global__ void fin_kernel(const double* __restrict__ acc, float* __restrict__ out) {
    if (threadIdx.x == 0) {
        const double recon  = acc[0] / (double)(NBATCH * NPTS * 3);
        const double percep = acc[1] / 4096.0;
        const double cont   = acc[2] / (double)(NBATCH * NPTS * KNN);
        const double cnt    = acc[4];
        const double bnd    = (cnt > 0.0) ? acc[3] / ((cnt > 1.0) ? cnt : 1.0) : 0.0;
        const double total  = recon + 0.5 * percep + 0.5 * cont + bnd;
        out[0] = (float)recon;
        out[1] = (float)percep;
        out[2] = (float)cont;
        out[3] = (float)bnd;
        out[4] = (float)total;
    }
}

extern "C" void kernel_launch(void* const* d_in, const int* in_sizes, int n_in,
                              void* d_out, int out_size, void* d_ws, size_t ws_size,
                              hipStream_t stream) {
    const float* pred = (const float*)d_in[0];
    const float* targ = (const float*)d_in[1];
    const float* pf   = (const float*)d_in[2];
    const float* tf   = (const float*)d_in[3];
    const float* c1   = (const float*)d_in[4];
    const float* c2   = (const float*)d_in[5];
    float* out  = (float*)d_out;
    double* acc = (double*)d_ws;
    float* pb   = (float*)((char*)d_ws + PB_OFF);

    hipMemsetAsync(d_ws, 0, 64, stream);   // acc[0..4]
    hipLaunchKernelGGL(prep_kernel, dim3(32), dim3(512), 0, stream, pred, pb);
    hipLaunchKernelGGL(mega_kernel, dim3(SCAN_BLOCKS), dim3(1024), 0, stream,
                       pb, pred, targ, pf, tf, c1, c2, acc);
    hipLaunchKernelGGL(fin_kernel, dim3(1), dim3(64), 0, stream, acc, out);
}